// Round 1
// baseline (1115.044 us; speedup 1.0000x reference)
//
#include <hip/hip_runtime.h>

typedef unsigned int u32;
typedef unsigned long long u64;
typedef u32   v4u __attribute__((ext_vector_type(4)));
typedef float v4f __attribute__((ext_vector_type(4)));

#define NN 100000
#define NE 3200000
#define DF 64
#define ALPHA 0.1f
#define BETA 0.9f
#define K_STEPS 10

#define EPTE 8                      // edges per thread (hist & scatter)
#define EB   (256 * EPTE)           // 2048 edges per block
#define NEB  ((NE + EB - 1) / EB)   // 1563 blocks
#define NSCB ((NN + 1023) / 1024)   // 98 scan chunks

// bf16 round-to-nearest-even -> 16-bit pattern
__device__ __forceinline__ u32 rne_bf16(float f) {
    u32 u = __float_as_uint(f);
    return (u + 0x7FFFu + ((u >> 16) & 1u)) >> 16;
}
__device__ __forceinline__ float bf_lo(u32 w) { return __uint_as_float(w << 16); }
__device__ __forceinline__ float bf_hi(u32 w) { return __uint_as_float(w & 0xFFFF0000u); }

// ---- P1: per-row histogram (plain global atomics, L2-resident bins) -----
__global__ void row_hist(const int* __restrict__ row, int* __restrict__ rcnt) {
    int base = blockIdx.x * EB + threadIdx.x;
    #pragma unroll
    for (int j = 0; j < EPTE; ++j) {
        int e = base + j * 256;
        if (e < NE) atomicAdd(&rcnt[row[e]], 1);
    }
}

// ---- P2a: 1024-wide chunked inclusive scan, emit chunk totals -----------
__global__ void scan_a(const int* __restrict__ rcnt, int* __restrict__ rtmp,
                       int* __restrict__ rpart) {
    __shared__ int s[1024];
    int i = blockIdx.x * 1024 + threadIdx.x;
    int v = (i < NN) ? rcnt[i] : 0;
    s[threadIdx.x] = v;
    __syncthreads();
    for (int off = 1; off < 1024; off <<= 1) {
        int t = (threadIdx.x >= off) ? s[threadIdx.x - off] : 0;
        __syncthreads();
        s[threadIdx.x] += t;
        __syncthreads();
    }
    if (i < NN) rtmp[i] = s[threadIdx.x];
    if (threadIdx.x == 1023) rpart[blockIdx.x] = s[1023];
}

// ---- P2b: exclusive scan of the 98 chunk totals (one block) -------------
__global__ void scan_b(int* __restrict__ rpart) {
    __shared__ int s[128];
    int i = threadIdx.x;
    int v = (i < NSCB) ? rpart[i] : 0;
    s[i] = v;
    __syncthreads();
    for (int off = 1; off < 128; off <<= 1) {
        int t = (i >= off) ? s[i - off] : 0;
        __syncthreads();
        s[i] += t;
        __syncthreads();
    }
    if (i < NSCB) rpart[i] = s[i] - v;   // exclusive
}

// ---- P2c: fixup -> rp (global inclusive end) + rcur (exclusive start) ---
__global__ void scan_c(const int* __restrict__ rtmp, const int* __restrict__ rpart,
                       const int* __restrict__ rcnt, int* __restrict__ rp,
                       int* __restrict__ rcur) {
    int i = blockIdx.x * 256 + threadIdx.x;
    if (i < NN) {
        int inc = rtmp[i] + rpart[i >> 10];
        rp[i] = inc;
        rcur[i] = inc - rcnt[i];
    }
}

// ---- P3: single-pass rank scatter into final packed edge array ----------
// entry = col<<15 | bf16(w)[14:0]
__global__ void scatter_edges(const int* __restrict__ row, const int* __restrict__ col,
                              const float* __restrict__ w, int* __restrict__ rcur,
                              u32* __restrict__ edgesF) {
    int base = blockIdx.x * EB + threadIdx.x;
    #pragma unroll
    for (int j = 0; j < EPTE; ++j) {
        int e = base + j * 256;
        if (e < NE) {
            int r = row[e];
            u32 cw = ((u32)col[e] << 15) | (rne_bf16(w[e]) & 0x7FFFu);
            int pos = atomicAdd(&rcur[r], 1);
            edgesF[pos] = cw;
        }
    }
}

// ---- x (f32) -> bf16 rows (h_0 and alpha-term) --------------------------
__global__ void conv_x(const float* __restrict__ x, u32* __restrict__ xb) {
    int t = blockIdx.x * blockDim.x + threadIdx.x;
    if (t >= NN * 8) return;
    const float4* src = (const float4*)(x + (size_t)t * 8);
    float4 a = src[0], b = src[1];
    uint4 o;
    o.x = rne_bf16(a.x) | (rne_bf16(a.y) << 16);
    o.y = rne_bf16(a.z) | (rne_bf16(a.w) << 16);
    o.z = rne_bf16(b.x) | (rne_bf16(b.y) << 16);
    o.w = rne_bf16(b.z) | (rne_bf16(b.w) << 16);
    *(uint4*)(xb + (size_t)t * 4) = o;
}

// ---- propagation: one wave per node, slice x feature-group lanes --------
__global__ __launch_bounds__(256) void
gather_step(const int* __restrict__ rp, const u32* __restrict__ edges,
            const u32* __restrict__ h, const u32* __restrict__ xb,
            u32* __restrict__ hn, float* __restrict__ outf, int final_step) {
    int lane = threadIdx.x & 63;
    int node = blockIdx.x * 4 + (threadIdx.x >> 6);
    int slice = lane >> 3;
    int fg = lane & 7;

    int start = (node == 0) ? 0 : rp[node - 1];
    int end = rp[node];

    float a0=0.f,a1=0.f,a2=0.f,a3=0.f,a4=0.f,a5=0.f,a6=0.f,a7=0.f;
    #pragma unroll 2
    for (int e = start + slice; e < end; e += 8) {
        u32 ew = __builtin_nontemporal_load(edges + e);
        u32 c = ew >> 15;
        float wv = __uint_as_float((ew & 0x7FFFu) << 16);
        const uint4 hv = *(const uint4*)(h + ((size_t)c << 5) + (fg << 2));
        a0 += wv * bf_lo(hv.x); a1 += wv * bf_hi(hv.x);
        a2 += wv * bf_lo(hv.y); a3 += wv * bf_hi(hv.y);
        a4 += wv * bf_lo(hv.z); a5 += wv * bf_hi(hv.z);
        a6 += wv * bf_lo(hv.w); a7 += wv * bf_hi(hv.w);
    }
    for (int m = 8; m <= 32; m <<= 1) {
        a0 += __shfl_xor(a0, m, 64); a1 += __shfl_xor(a1, m, 64);
        a2 += __shfl_xor(a2, m, 64); a3 += __shfl_xor(a3, m, 64);
        a4 += __shfl_xor(a4, m, 64); a5 += __shfl_xor(a5, m, 64);
        a6 += __shfl_xor(a6, m, 64); a7 += __shfl_xor(a7, m, 64);
    }
    uint4 xv = *(const uint4*)(xb + ((size_t)node << 5) + (fg << 2));
    float o0 = BETA * a0 + ALPHA * bf_lo(xv.x);
    float o1 = BETA * a1 + ALPHA * bf_hi(xv.x);
    float o2 = BETA * a2 + ALPHA * bf_lo(xv.y);
    float o3 = BETA * a3 + ALPHA * bf_hi(xv.y);
    float o4 = BETA * a4 + ALPHA * bf_lo(xv.z);
    float o5 = BETA * a5 + ALPHA * bf_hi(xv.z);
    float o6 = BETA * a6 + ALPHA * bf_lo(xv.w);
    float o7 = BETA * a7 + ALPHA * bf_hi(xv.w);

    if (!final_step) {
        if (slice == 0) {
            v4u o;
            o.x = rne_bf16(o0) | (rne_bf16(o1) << 16);
            o.y = rne_bf16(o2) | (rne_bf16(o3) << 16);
            o.z = rne_bf16(o4) | (rne_bf16(o5) << 16);
            o.w = rne_bf16(o6) | (rne_bf16(o7) << 16);
            __builtin_nontemporal_store(o, (v4u*)(hn + ((size_t)node << 5) + (fg << 2)));
        }
    } else {
        if (slice < 2) {
            v4f v;
            if (slice) { v.x = o4; v.y = o5; v.z = o6; v.w = o7; }
            else       { v.x = o0; v.y = o1; v.z = o2; v.w = o3; }
            __builtin_nontemporal_store(v, (v4f*)(outf + (size_t)node * DF + fg * 8 + slice * 4));
        }
    }
}

// ---- launch -------------------------------------------------------------

extern "C" void kernel_launch(void* const* d_in, const int* in_sizes, int n_in,
                              void* d_out, int out_size, void* d_ws, size_t ws_size,
                              hipStream_t stream) {
    const float* x    = (const float*)d_in[0];
    const int*   erow = (const int*)  d_in[1];
    const int*   ecol = (const int*)  d_in[2];
    const float* ew   = (const float*)d_in[3];
    float* out = (float*)d_out;

    char* ws = (char*)d_ws;
    u32* edgesF = (u32*)(ws);                     // 12,800,000 B final packed edges
    u32* xb     = (u32*)(ws + 12800000);          // 12,800,000 B bf16 x (= h_0)
    u32* hA     = (u32*)(ws + 25600000);          // 12,800,000 B
    u32* hB     = (u32*)(ws + 38400000);          // 12,800,000 B
    int* rp     = (int*)(ws + 51200000);          //    400,000 B end offsets
    // preprocessing temps alias hA (dead before k=0 gather fully rewrites hA)
    int* rcnt   = (int*)(ws + 25600000);          //    400,000 B per-row counts
    int* rtmp   = (int*)(ws + 26000000);          //    400,000 B chunk-scanned counts
    int* rcur   = (int*)(ws + 26400000);          //    400,000 B scatter cursors
    int* rpart  = (int*)(ws + 26800000);          //        512 B chunk totals

    dim3 blk(256);
    dim3 gE(NEB);                                 // 1563 edge blocks
    dim3 gConv((NN * 8 + 255) / 256);             // 3125
    dim3 gG(NN / 4);                              // 25000 blocks, 1 wave/node

    (void)hipMemsetAsync(rcnt, 0, NN * sizeof(int), stream);
    row_hist<<<gE, blk, 0, stream>>>(erow, rcnt);
    scan_a<<<dim3(NSCB), dim3(1024), 0, stream>>>(rcnt, rtmp, rpart);
    scan_b<<<dim3(1), dim3(128), 0, stream>>>(rpart);
    scan_c<<<dim3((NN + 255) / 256), blk, 0, stream>>>(rtmp, rpart, rcnt, rp, rcur);
    scatter_edges<<<gE, blk, 0, stream>>>(erow, ecol, ew, rcur, edgesF);
    conv_x<<<gConv, blk, 0, stream>>>(x, xb);

    // k=0 reads xb; then ping-pong hA/hB; k=9 writes f32 out
    for (int k = 0; k < K_STEPS; ++k) {
        const u32* src = (k == 0) ? xb : ((k & 1) ? hA : hB);
        u32* dst = (k & 1) ? hB : hA;
        int fin = (k == K_STEPS - 1);
        gather_step<<<gG, blk, 0, stream>>>(rp, edgesF, src, xb,
                                            fin ? nullptr : dst,
                                            fin ? out : nullptr, fin);
    }
}

// Round 2
// 905.674 us; speedup vs baseline: 1.2312x; 1.2312x over previous
//
#include <hip/hip_runtime.h>

typedef unsigned int u32;
typedef unsigned long long u64;
typedef u32   v4u __attribute__((ext_vector_type(4)));
typedef float v4f __attribute__((ext_vector_type(4)));

#define NN 100000
#define NE 3200000
#define DF 64
#define ALPHA 0.1f
#define BETA 0.9f
#define K_STEPS 10
#define NBKT 782              // ceil(NN/128) row buckets, 128 rows each
#define EPT 8                 // edges per thread in bucket passes
#define CHUNK (256 * EPT)     // 2048 edges per block
#define NCHB ((NE + CHUNK - 1) / CHUNK)   // 1563 chunks
#define BRT 512               // build_rows threads

// bf16 round-to-nearest-even -> 16-bit pattern
__device__ __forceinline__ u32 rne_bf16(float f) {
    u32 u = __float_as_uint(f);
    return (u + 0x7FFFu + ((u >> 16) & 1u)) >> 16;
}
__device__ __forceinline__ float bf_lo(u32 w) { return __uint_as_float(w << 16); }
__device__ __forceinline__ float bf_hi(u32 w) { return __uint_as_float(w & 0xFFFF0000u); }

// ---- A1: bucket histogram (LDS-privatized) ------------------------------
__global__ void bucket_hist(const int* __restrict__ row, int* __restrict__ bcnt) {
    __shared__ int s[NBKT];
    for (int i = threadIdx.x; i < NBKT; i += 256) s[i] = 0;
    __syncthreads();
    int base = blockIdx.x * CHUNK + threadIdx.x;
    #pragma unroll
    for (int j = 0; j < EPT; ++j) {
        int e = base + j * 256;
        if (e < NE) atomicAdd(&s[row[e] >> 7], 1);
    }
    __syncthreads();
    for (int i = threadIdx.x; i < NBKT; i += 256) {
        int v = s[i];
        if (v) atomicAdd(&bcnt[i], v);
    }
}

// ---- scan of 782 bucket counts -> bases + cursors (one block) -----------
__global__ void scan_buckets(const int* __restrict__ bcnt, int* __restrict__ bbase,
                             int* __restrict__ bcur) {
    __shared__ int s[1024];
    int i = threadIdx.x;
    int v = (i < NBKT) ? bcnt[i] : 0;
    s[i] = v;
    __syncthreads();
    for (int off = 1; off < 1024; off <<= 1) {
        int t = (i >= off) ? s[i - off] : 0;
        __syncthreads();
        s[i] += t;
        __syncthreads();
    }
    if (i < NBKT) { int b = s[i] - v; bbase[i] = b; bcur[i] = b; }
}

// ---- A2: scatter packed u64 entries into bucket regions -----------------
// entry = (row&127)<<32 | col<<15 | bf16(w)[14:0]
__global__ void bucket_scatter(const int* __restrict__ row, const int* __restrict__ col,
                               const float* __restrict__ w, int* __restrict__ bcur,
                               u64* __restrict__ e64) {
    __shared__ int scnt[NBKT];
    __shared__ int sbase[NBKT];
    for (int i = threadIdx.x; i < NBKT; i += 256) scnt[i] = 0;
    __syncthreads();
    int base = blockIdx.x * CHUNK + threadIdx.x;
    int rows[EPT];
    #pragma unroll
    for (int j = 0; j < EPT; ++j) {
        int e = base + j * 256;
        int r = (e < NE) ? row[e] : -1;
        rows[j] = r;
        if (r >= 0) atomicAdd(&scnt[r >> 7], 1);
    }
    __syncthreads();
    for (int i = threadIdx.x; i < NBKT; i += 256) {
        int c = scnt[i];
        sbase[i] = c ? atomicAdd(&bcur[i], c) : 0;
    }
    __syncthreads();
    for (int i = threadIdx.x; i < NBKT; i += 256) scnt[i] = 0;
    __syncthreads();
    #pragma unroll
    for (int j = 0; j < EPT; ++j) {
        int e = base + j * 256;
        int r = rows[j];
        if (r >= 0) {
            int b = r >> 7;
            int rank = atomicAdd(&scnt[b], 1);
            u32 cw = ((u32)col[e] << 15) | (rne_bf16(w[e]) & 0x7FFFu);
            e64[sbase[b] + rank] = ((u64)(r & 127) << 32) | cw;
        }
    }
}

// ---- B: per-bucket local CSR: rp + final packed u32 edges ---------------
__global__ void build_rows(const u64* __restrict__ e64, const int* __restrict__ bcnt,
                           const int* __restrict__ bbase, u32* __restrict__ edgesF,
                           int* __restrict__ rp) {
    __shared__ int rc[128];   // counts, then exclusive cursors
    __shared__ int rb[128];   // inclusive scan
    int b = blockIdx.x;
    int cnt = bcnt[b], base = bbase[b];
    if (threadIdx.x < 128) rc[threadIdx.x] = 0;
    __syncthreads();
    for (int e = threadIdx.x; e < cnt; e += BRT)
        atomicAdd(&rc[(int)(e64[base + e] >> 32)], 1);
    __syncthreads();
    if (threadIdx.x < 128) rb[threadIdx.x] = rc[threadIdx.x];
    __syncthreads();
    for (int off = 1; off < 128; off <<= 1) {
        int t = (threadIdx.x < 128 && threadIdx.x >= off) ? rb[threadIdx.x - off] : 0;
        __syncthreads();
        if (threadIdx.x < 128) rb[threadIdx.x] += t;
        __syncthreads();
    }
    if (threadIdx.x < 128) {
        int r = b * 128 + threadIdx.x;
        if (r < NN) rp[r] = base + rb[threadIdx.x];      // global end offset
        rc[threadIdx.x] = rb[threadIdx.x] - rc[threadIdx.x];  // exclusive cursor
    }
    __syncthreads();
    for (int e = threadIdx.x; e < cnt; e += BRT) {
        u64 ent = e64[base + e];
        int pos = atomicAdd(&rc[(int)(ent >> 32)], 1);
        edgesF[base + pos] = (u32)ent;
    }
}

// ---- x (f32) -> bf16 rows (h_0 and alpha-term) --------------------------
__global__ void conv_x(const float* __restrict__ x, u32* __restrict__ xb) {
    int t = blockIdx.x * blockDim.x + threadIdx.x;
    if (t >= NN * 8) return;
    const float4* src = (const float4*)(x + (size_t)t * 8);
    float4 a = src[0], b = src[1];
    uint4 o;
    o.x = rne_bf16(a.x) | (rne_bf16(a.y) << 16);
    o.y = rne_bf16(a.z) | (rne_bf16(a.w) << 16);
    o.z = rne_bf16(b.x) | (rne_bf16(b.y) << 16);
    o.w = rne_bf16(b.z) | (rne_bf16(b.w) << 16);
    *(uint4*)(xb + (size_t)t * 4) = o;
}

// ---- propagation: one wave per node, slice x feature-group lanes --------
__global__ __launch_bounds__(256) void
gather_step(const int* __restrict__ rp, const u32* __restrict__ edges,
            const u32* __restrict__ h, const u32* __restrict__ xb,
            u32* __restrict__ hn, float* __restrict__ outf, int final_step) {
    int lane = threadIdx.x & 63;
    int node = blockIdx.x * 4 + (threadIdx.x >> 6);
    int slice = lane >> 3;
    int fg = lane & 7;

    int start = (node == 0) ? 0 : rp[node - 1];
    int end = rp[node];

    float a0=0.f,a1=0.f,a2=0.f,a3=0.f,a4=0.f,a5=0.f,a6=0.f,a7=0.f;
    #pragma unroll 2
    for (int e = start + slice; e < end; e += 8) {
        u32 ew = __builtin_nontemporal_load(edges + e);
        u32 c = ew >> 15;
        float wv = __uint_as_float((ew & 0x7FFFu) << 16);
        const uint4 hv = *(const uint4*)(h + ((size_t)c << 5) + (fg << 2));
        a0 += wv * bf_lo(hv.x); a1 += wv * bf_hi(hv.x);
        a2 += wv * bf_lo(hv.y); a3 += wv * bf_hi(hv.y);
        a4 += wv * bf_lo(hv.z); a5 += wv * bf_hi(hv.z);
        a6 += wv * bf_lo(hv.w); a7 += wv * bf_hi(hv.w);
    }
    for (int m = 8; m <= 32; m <<= 1) {
        a0 += __shfl_xor(a0, m, 64); a1 += __shfl_xor(a1, m, 64);
        a2 += __shfl_xor(a2, m, 64); a3 += __shfl_xor(a3, m, 64);
        a4 += __shfl_xor(a4, m, 64); a5 += __shfl_xor(a5, m, 64);
        a6 += __shfl_xor(a6, m, 64); a7 += __shfl_xor(a7, m, 64);
    }
    uint4 xv = *(const uint4*)(xb + ((size_t)node << 5) + (fg << 2));
    float o0 = BETA * a0 + ALPHA * bf_lo(xv.x);
    float o1 = BETA * a1 + ALPHA * bf_hi(xv.x);
    float o2 = BETA * a2 + ALPHA * bf_lo(xv.y);
    float o3 = BETA * a3 + ALPHA * bf_hi(xv.y);
    float o4 = BETA * a4 + ALPHA * bf_lo(xv.z);
    float o5 = BETA * a5 + ALPHA * bf_hi(xv.z);
    float o6 = BETA * a6 + ALPHA * bf_lo(xv.w);
    float o7 = BETA * a7 + ALPHA * bf_hi(xv.w);

    if (!final_step) {
        if (slice == 0) {
            v4u o;
            o.x = rne_bf16(o0) | (rne_bf16(o1) << 16);
            o.y = rne_bf16(o2) | (rne_bf16(o3) << 16);
            o.z = rne_bf16(o4) | (rne_bf16(o5) << 16);
            o.w = rne_bf16(o6) | (rne_bf16(o7) << 16);
            __builtin_nontemporal_store(o, (v4u*)(hn + ((size_t)node << 5) + (fg << 2)));
        }
    } else {
        if (slice < 2) {
            v4f v;
            if (slice) { v.x = o4; v.y = o5; v.z = o6; v.w = o7; }
            else       { v.x = o0; v.y = o1; v.z = o2; v.w = o3; }
            __builtin_nontemporal_store(v, (v4f*)(outf + (size_t)node * DF + fg * 8 + slice * 4));
        }
    }
}

// ---- launch -------------------------------------------------------------

extern "C" void kernel_launch(void* const* d_in, const int* in_sizes, int n_in,
                              void* d_out, int out_size, void* d_ws, size_t ws_size,
                              hipStream_t stream) {
    const float* x    = (const float*)d_in[0];
    const int*   erow = (const int*)  d_in[1];
    const int*   ecol = (const int*)  d_in[2];
    const float* ew   = (const float*)d_in[3];
    float* out = (float*)d_out;

    char* ws = (char*)d_ws;
    u32* edgesF = (u32*)(ws);                     // 12,800,000 B final packed edges
    u32* xb     = (u32*)(ws + 12800000);          // 12,800,000 B bf16 x (= h_0)
    u32* hA     = (u32*)(ws + 25600000);          // 12,800,000 B
    u32* hB     = (u32*)(ws + 38400000);          // 12,800,000 B
    u64* e64    = (u64*)(ws + 25600000);          // 25,600,000 B — aliases hA+hB (dead before gathers)
    int* rp     = (int*)(ws + 51200000);          //    400,000 B
    int* bcnt   = (int*)(ws + 51600000);          //      3,128 B
    int* bbase  = (int*)(ws + 51604096);          //      3,128 B
    int* bcur   = (int*)(ws + 51608192);          //      3,128 B

    dim3 blk(256);
    dim3 gChunk(NCHB);                            // 1563
    dim3 gConv((NN * 8 + 255) / 256);             // 3125
    dim3 gG(NN / 4);                              // 25000 blocks, 1 wave/node

    (void)hipMemsetAsync(bcnt, 0, NBKT * sizeof(int), stream);
    bucket_hist<<<gChunk, blk, 0, stream>>>(erow, bcnt);
    scan_buckets<<<1, 1024, 0, stream>>>(bcnt, bbase, bcur);
    bucket_scatter<<<gChunk, blk, 0, stream>>>(erow, ecol, ew, bcur, e64);
    build_rows<<<NBKT, dim3(BRT), 0, stream>>>(e64, bcnt, bbase, edgesF, rp);
    conv_x<<<gConv, blk, 0, stream>>>(x, xb);

    // k=0 reads xb; then ping-pong hA/hB; k=9 writes f32 out
    for (int k = 0; k < K_STEPS; ++k) {
        const u32* src = (k == 0) ? xb : ((k & 1) ? hA : hB);
        u32* dst = (k & 1) ? hB : hA;
        int fin = (k == K_STEPS - 1);
        gather_step<<<gG, blk, 0, stream>>>(rp, edgesF, src, xb,
                                            fin ? nullptr : dst,
                                            fin ? out : nullptr, fin);
    }
}

// Round 3
// 872.164 us; speedup vs baseline: 1.2785x; 1.0384x over previous
//
#include <hip/hip_runtime.h>

typedef unsigned int u32;
typedef unsigned long long u64;
typedef u32   v4u __attribute__((ext_vector_type(4)));
typedef float v4f __attribute__((ext_vector_type(4)));

#define NN 100000
#define NE 3200000
#define DF 64
#define ALPHA 0.1f
#define BETA 0.9f
#define K_STEPS 10
#define NBKT 782              // ceil(NN/128) row buckets, 128 rows each
#define EPT 16                // edges per thread in bucket passes (round-0 verified)
#define CHUNK (256 * EPT)     // 4096 edges per block
#define NCHB ((NE + CHUNK - 1) / CHUNK)   // 782 chunks
#define NKEY 1024             // 128 rows x 8 col-ranges per bucket

// bf16 round-to-nearest-even -> 16-bit pattern
__device__ __forceinline__ u32 rne_bf16(float f) {
    u32 u = __float_as_uint(f);
    return (u + 0x7FFFu + ((u >> 16) & 1u)) >> 16;
}
__device__ __forceinline__ float bf_lo(u32 w) { return __uint_as_float(w << 16); }
__device__ __forceinline__ float bf_hi(u32 w) { return __uint_as_float(w & 0xFFFF0000u); }

// ---- A1: bucket histogram (LDS-privatized) ------------------------------
__global__ void bucket_hist(const int* __restrict__ row, int* __restrict__ bcnt) {
    __shared__ int s[NBKT];
    for (int i = threadIdx.x; i < NBKT; i += 256) s[i] = 0;
    __syncthreads();
    int base = blockIdx.x * CHUNK + threadIdx.x;
    #pragma unroll
    for (int j = 0; j < EPT; ++j) {
        int e = base + j * 256;
        if (e < NE) atomicAdd(&s[row[e] >> 7], 1);
    }
    __syncthreads();
    for (int i = threadIdx.x; i < NBKT; i += 256) {
        int v = s[i];
        if (v) atomicAdd(&bcnt[i], v);
    }
}

// ---- scan of 782 bucket counts -> bases + cursors (one block) -----------
__global__ void scan_buckets(const int* __restrict__ bcnt, int* __restrict__ bbase,
                             int* __restrict__ bcur) {
    __shared__ int s[1024];
    int i = threadIdx.x;
    int v = (i < NBKT) ? bcnt[i] : 0;
    s[i] = v;
    __syncthreads();
    for (int off = 1; off < 1024; off <<= 1) {
        int t = (i >= off) ? s[i - off] : 0;
        __syncthreads();
        s[i] += t;
        __syncthreads();
    }
    if (i < NBKT) { int b = s[i] - v; bbase[i] = b; bcur[i] = b; }
}

// ---- A2: scatter packed u64 entries into bucket regions -----------------
// entry = key<<32 | col<<15 | bf16(w)[14:0], key = (row&127)<<3 | (col>>14)
__global__ void bucket_scatter(const int* __restrict__ row, const int* __restrict__ col,
                               const float* __restrict__ w, int* __restrict__ bcur,
                               u64* __restrict__ e64) {
    __shared__ int scnt[NBKT];
    __shared__ int sbase[NBKT];
    for (int i = threadIdx.x; i < NBKT; i += 256) scnt[i] = 0;
    __syncthreads();
    int base = blockIdx.x * CHUNK + threadIdx.x;
    int rows[EPT];
    #pragma unroll
    for (int j = 0; j < EPT; ++j) {
        int e = base + j * 256;
        int r = (e < NE) ? row[e] : -1;
        rows[j] = r;
        if (r >= 0) atomicAdd(&scnt[r >> 7], 1);
    }
    __syncthreads();
    for (int i = threadIdx.x; i < NBKT; i += 256) {
        int c = scnt[i];
        sbase[i] = c ? atomicAdd(&bcur[i], c) : 0;
    }
    __syncthreads();
    for (int i = threadIdx.x; i < NBKT; i += 256) scnt[i] = 0;
    __syncthreads();
    #pragma unroll
    for (int j = 0; j < EPT; ++j) {
        int e = base + j * 256;
        int r = rows[j];
        if (r >= 0) {
            int b = r >> 7;
            int rank = atomicAdd(&scnt[b], 1);
            u32 c = (u32)col[e];
            u32 cw = (c << 15) | (rne_bf16(w[e]) & 0x7FFFu);
            u32 key = ((u32)(r & 127) << 3) | (c >> 14);   // col-range phase in low 3 bits
            e64[sbase[b] + rank] = ((u64)key << 32) | cw;
        }
    }
}

// ---- B: per-bucket counting sort by (row, col-range): rp + packed edges --
__global__ __launch_bounds__(1024) void
build_rows(const u64* __restrict__ e64, const int* __restrict__ bcnt,
           const int* __restrict__ bbase, u32* __restrict__ edgesF,
           int* __restrict__ rp) {
    __shared__ int rc[NKEY];   // counts, then exclusive cursors
    __shared__ int rb[NKEY];   // inclusive scan
    int b = blockIdx.x;
    int tid = threadIdx.x;
    int cnt = bcnt[b], base = bbase[b];
    rc[tid] = 0;
    __syncthreads();
    for (int e = tid; e < cnt; e += 1024)
        atomicAdd(&rc[(int)(e64[base + e] >> 32)], 1);
    __syncthreads();
    rb[tid] = rc[tid];
    __syncthreads();
    for (int off = 1; off < 1024; off <<= 1) {
        int t = (tid >= off) ? rb[tid - off] : 0;
        __syncthreads();
        rb[tid] += t;
        __syncthreads();
    }
    if ((tid & 7) == 7) {                        // key = localrow*8+7 -> row end
        int r = b * 128 + (tid >> 3);
        if (r < NN) rp[r] = base + rb[tid];      // global end offset
    }
    rc[tid] = rb[tid] - rc[tid];                 // exclusive cursor per key
    __syncthreads();
    for (int e = tid; e < cnt; e += 1024) {
        u64 ent = e64[base + e];
        int pos = atomicAdd(&rc[(int)(ent >> 32)], 1);
        edgesF[base + pos] = (u32)ent;
    }
}

// ---- x (f32) -> bf16 rows (h_0 and alpha-term) --------------------------
__global__ void conv_x(const float* __restrict__ x, u32* __restrict__ xb) {
    int t = blockIdx.x * blockDim.x + threadIdx.x;
    if (t >= NN * 8) return;
    const float4* src = (const float4*)(x + (size_t)t * 8);
    float4 a = src[0], b = src[1];
    uint4 o;
    o.x = rne_bf16(a.x) | (rne_bf16(a.y) << 16);
    o.y = rne_bf16(a.z) | (rne_bf16(a.w) << 16);
    o.z = rne_bf16(b.x) | (rne_bf16(b.y) << 16);
    o.w = rne_bf16(b.z) | (rne_bf16(b.w) << 16);
    *(uint4*)(xb + (size_t)t * 4) = o;
}

// ---- propagation: one wave per node, slice x feature-group lanes --------
__global__ __launch_bounds__(256) void
gather_step(const int* __restrict__ rp, const u32* __restrict__ edges,
            const u32* __restrict__ h, const u32* __restrict__ xb,
            u32* __restrict__ hn, float* __restrict__ outf, int final_step) {
    int lane = threadIdx.x & 63;
    int node = blockIdx.x * 4 + (threadIdx.x >> 6);
    int slice = lane >> 3;
    int fg = lane & 7;

    int start = (node == 0) ? 0 : rp[node - 1];
    int end = rp[node];

    float a0=0.f,a1=0.f,a2=0.f,a3=0.f,a4=0.f,a5=0.f,a6=0.f,a7=0.f;
    #pragma unroll 4
    for (int e = start + slice; e < end; e += 8) {
        u32 ew = __builtin_nontemporal_load(edges + e);
        u32 c = ew >> 15;
        float wv = __uint_as_float((ew & 0x7FFFu) << 16);
        const uint4 hv = *(const uint4*)(h + ((size_t)c << 5) + (fg << 2));
        a0 += wv * bf_lo(hv.x); a1 += wv * bf_hi(hv.x);
        a2 += wv * bf_lo(hv.y); a3 += wv * bf_hi(hv.y);
        a4 += wv * bf_lo(hv.z); a5 += wv * bf_hi(hv.z);
        a6 += wv * bf_lo(hv.w); a7 += wv * bf_hi(hv.w);
    }
    for (int m = 8; m <= 32; m <<= 1) {
        a0 += __shfl_xor(a0, m, 64); a1 += __shfl_xor(a1, m, 64);
        a2 += __shfl_xor(a2, m, 64); a3 += __shfl_xor(a3, m, 64);
        a4 += __shfl_xor(a4, m, 64); a5 += __shfl_xor(a5, m, 64);
        a6 += __shfl_xor(a6, m, 64); a7 += __shfl_xor(a7, m, 64);
    }
    uint4 xv = *(const uint4*)(xb + ((size_t)node << 5) + (fg << 2));
    float o0 = BETA * a0 + ALPHA * bf_lo(xv.x);
    float o1 = BETA * a1 + ALPHA * bf_hi(xv.x);
    float o2 = BETA * a2 + ALPHA * bf_lo(xv.y);
    float o3 = BETA * a3 + ALPHA * bf_hi(xv.y);
    float o4 = BETA * a4 + ALPHA * bf_lo(xv.z);
    float o5 = BETA * a5 + ALPHA * bf_hi(xv.z);
    float o6 = BETA * a6 + ALPHA * bf_lo(xv.w);
    float o7 = BETA * a7 + ALPHA * bf_hi(xv.w);

    if (!final_step) {
        if (slice == 0) {
            v4u o;
            o.x = rne_bf16(o0) | (rne_bf16(o1) << 16);
            o.y = rne_bf16(o2) | (rne_bf16(o3) << 16);
            o.z = rne_bf16(o4) | (rne_bf16(o5) << 16);
            o.w = rne_bf16(o6) | (rne_bf16(o7) << 16);
            __builtin_nontemporal_store(o, (v4u*)(hn + ((size_t)node << 5) + (fg << 2)));
        }
    } else {
        if (slice < 2) {
            v4f v;
            if (slice) { v.x = o4; v.y = o5; v.z = o6; v.w = o7; }
            else       { v.x = o0; v.y = o1; v.z = o2; v.w = o3; }
            __builtin_nontemporal_store(v, (v4f*)(outf + (size_t)node * DF + fg * 8 + slice * 4));
        }
    }
}

// ---- launch -------------------------------------------------------------

extern "C" void kernel_launch(void* const* d_in, const int* in_sizes, int n_in,
                              void* d_out, int out_size, void* d_ws, size_t ws_size,
                              hipStream_t stream) {
    const float* x    = (const float*)d_in[0];
    const int*   erow = (const int*)  d_in[1];
    const int*   ecol = (const int*)  d_in[2];
    const float* ew   = (const float*)d_in[3];
    float* out = (float*)d_out;

    char* ws = (char*)d_ws;
    u32* edgesF = (u32*)(ws);                     // 12,800,000 B final packed edges
    u32* xb     = (u32*)(ws + 12800000);          // 12,800,000 B bf16 x (= h_0)
    u32* hA     = (u32*)(ws + 25600000);          // 12,800,000 B
    u32* hB     = (u32*)(ws + 38400000);          // 12,800,000 B
    u64* e64    = (u64*)(ws + 25600000);          // 25,600,000 B — aliases hA+hB (dead before gathers)
    int* rp     = (int*)(ws + 51200000);          //    400,000 B
    int* bcnt   = (int*)(ws + 51600000);          //      3,128 B
    int* bbase  = (int*)(ws + 51604096);          //      3,128 B
    int* bcur   = (int*)(ws + 51608192);          //      3,128 B

    dim3 blk(256);
    dim3 gChunk(NCHB);                            // 782
    dim3 gConv((NN * 8 + 255) / 256);             // 3125
    dim3 gG(NN / 4);                              // 25000 blocks, 1 wave/node

    (void)hipMemsetAsync(bcnt, 0, NBKT * sizeof(int), stream);
    bucket_hist<<<gChunk, blk, 0, stream>>>(erow, bcnt);
    scan_buckets<<<1, 1024, 0, stream>>>(bcnt, bbase, bcur);
    bucket_scatter<<<gChunk, blk, 0, stream>>>(erow, ecol, ew, bcur, e64);
    build_rows<<<NBKT, dim3(1024), 0, stream>>>(e64, bcnt, bbase, edgesF, rp);
    conv_x<<<gConv, blk, 0, stream>>>(x, xb);

    // k=0 reads xb; then ping-pong hA/hB; k=9 writes f32 out
    for (int k = 0; k < K_STEPS; ++k) {
        const u32* src = (k == 0) ? xb : ((k & 1) ? hA : hB);
        u32* dst = (k & 1) ? hB : hA;
        int fin = (k == K_STEPS - 1);
        gather_step<<<gG, blk, 0, stream>>>(rp, edgesF, src, xb,
                                            fin ? nullptr : dst,
                                            fin ? out : nullptr, fin);
    }
}